// Round 2
// baseline (266.956 us; speedup 1.0000x reference)
//
#include <hip/hip_runtime.h>
#include <math.h>

// DifferentiableSoftmaxTree: hierarchical (binary-tree) softmax NLL.
// BATCH=4096, FDIM=512, DEPTH=16, NUM_INTERNAL=49999.
// One 64-lane wave per batch row. Lane i owns dims {4i..4i+3, 256+4i..256+4i+3}.
// Key observations vs round 1 (265us, latency-serialized):
//  - loss term depends only on z = l0 - l1, so accumulate per-lane partials of
//    f . (w[:,0]-w[:,1]) directly: halves FMAs and halves the shuffle reduce.
//  - accumulate ALL 16 levels' partials first with a 4-deep register pipeline
//    (16 outstanding dwordx4 loads/wave), THEN run the 16 butterfly reductions
//    as independent 6-shuffle chains (throughput-bound, not latency-chained).

constexpr int BATCH = 4096;
constexpr int FDIM  = 512;
constexpr int DEPTH = 16;

__global__ __launch_bounds__(256, 4) void hstree_loss(
    const float* __restrict__ features,
    const int*   __restrict__ targets,
    const float* __restrict__ node_weights,
    const int*   __restrict__ path_nodes,
    const int*   __restrict__ path_dirs,
    float*       __restrict__ out)
{
    const int lane = threadIdx.x & 63;
    const int b    = (blockIdx.x << 2) + (threadIdx.x >> 6);

    // wave-uniform target -> SGPR, so path-map reads become scalar loads
    const int t = __builtin_amdgcn_readfirstlane(targets[b]);

    int nodes[DEPTH];
    int dirs[DEPTH];
#pragma unroll
    for (int k = 0; k < DEPTH; ++k) {
        nodes[k] = path_nodes[t * DEPTH + k];
        dirs[k]  = path_dirs [t * DEPTH + k];
    }

    // features: two float4 per lane (issued early, consumed in the loop)
    const float4* fb = (const float4*)(features + (size_t)b * FDIM);
    const float4 f0 = fb[lane];        // dims 4*lane .. 4*lane+3
    const float4 f1 = fb[lane + 64];   // dims 256 + 4*lane ..

    // weight base for level k; padding (-1) -> node 0 (L2-hot, masked later)
    auto wptr = [&](int k) -> const float4* {
        const int n = nodes[k] < 0 ? 0 : nodes[k];
        return (const float4*)(node_weights + (size_t)n * (FDIM * 2));
    };

    const int o0 = 2 * lane;       // w[4l..4l+1][0..1]
    const int o1 = 2 * lane + 1;   // w[4l+2..4l+3][0..1]
    const int o2 = 128 + 2 * lane; // w[256+4l ..][0..1]
    const int o3 = 129 + 2 * lane;

    // 4-deep register pipeline: 16 outstanding 16B loads per wave
    float4 buf[4][4];
#pragma unroll
    for (int k = 0; k < 4; ++k) {
        const float4* p = wptr(k);
        buf[k][0] = p[o0]; buf[k][1] = p[o1];
        buf[k][2] = p[o2]; buf[k][3] = p[o3];
    }

    float zp[DEPTH];  // per-lane partial of (logit0 - logit1) per level
#pragma unroll
    for (int k = 0; k < DEPTH; ++k) {
        const float4 a0 = buf[k & 3][0], a1 = buf[k & 3][1];
        const float4 a2 = buf[k & 3][2], a3 = buf[k & 3][3];
        if (k + 4 < DEPTH) {  // refill the slot just consumed
            const float4* p = wptr(k + 4);
            buf[k & 3][0] = p[o0]; buf[k & 3][1] = p[o1];
            buf[k & 3][2] = p[o2]; buf[k & 3][3] = p[o3];
        }
        zp[k] = f0.x * (a0.x - a0.y) + f0.y * (a0.z - a0.w)
              + f0.z * (a1.x - a1.y) + f0.w * (a1.z - a1.w)
              + f1.x * (a2.x - a2.y) + f1.y * (a2.z - a2.w)
              + f1.z * (a3.x - a3.y) + f1.w * (a3.z - a3.w);
    }

    // 16 independent 6-level butterflies: pipelined through the LDS unit
#pragma unroll
    for (int k = 0; k < DEPTH; ++k) {
#pragma unroll
        for (int off = 32; off; off >>= 1)
            zp[k] += __shfl_xor(zp[k], off, 64);
    }

    // loss = sum_k softplus(l_other - l_dir) = softplus(-s), s = dir? -z : z
    float loss = 0.0f;
#pragma unroll
    for (int k = 0; k < DEPTH; ++k) {
        if (nodes[k] >= 0) {
            const float s = (dirs[k] == 0) ? zp[k] : -zp[k];
            loss += fmaxf(-s, 0.0f) + __logf(1.0f + __expf(-fabsf(s)));
        }
    }

    if (lane == 0) out[b] = loss;
}

extern "C" void kernel_launch(void* const* d_in, const int* in_sizes, int n_in,
                              void* d_out, int out_size, void* d_ws, size_t ws_size,
                              hipStream_t stream) {
    const float* features     = (const float*)d_in[0];
    const int*   targets      = (const int*)  d_in[1];
    const float* node_weights = (const float*)d_in[2];
    const int*   path_nodes   = (const int*)  d_in[3];
    const int*   path_dirs    = (const int*)  d_in[4];
    float*       out          = (float*)d_out;

    hstree_loss<<<BATCH / 4, 256, 0, stream>>>(
        features, targets, node_weights, path_nodes, path_dirs, out);
}

// Round 3
// 266.425 us; speedup vs baseline: 1.0020x; 1.0020x over previous
//
#include <hip/hip_runtime.h>
#include <math.h>

// DifferentiableSoftmaxTree: hierarchical (binary-tree) softmax NLL.
// BATCH=4096, FDIM=512, DEPTH=16, NUM_INTERNAL=49999.
// One 64-lane wave per batch row.
//
// R3 changes vs R2 (R1/R2 both ~identical -> memory-system service-rate
// bound, not MLP/compute bound):
//  - LEVEL ROTATION: row b walks levels in order (b&15)+j mod 16. De-phases
//    the 4096 waves so upper-level (L2-hot, same-line) and deep-level
//    (L3/HBM) requests mix instead of all waves hammering the same few
//    4KB rows in lockstep. Rotation is applied when loading the path maps,
//    so all register arrays keep static indices.
//  - CONTIGUOUS COALESCING: lane reads w4[lane + 64*q] -> each weight-load
//    instruction covers one contiguous 1KB (8 fully-used 128B lines),
//    instead of the R2 stride-32B pattern that half-used 16 lines.
//    Lane L owns dims {2L,2L+1} of each 128-dim quarter; features loaded
//    as 4x float2 to match.

constexpr int BATCH = 4096;
constexpr int FDIM  = 512;
constexpr int DEPTH = 16;

__global__ __launch_bounds__(256, 4) void hstree_loss(
    const float* __restrict__ features,
    const int*   __restrict__ targets,
    const float* __restrict__ node_weights,
    const int*   __restrict__ path_nodes,
    const int*   __restrict__ path_dirs,
    float*       __restrict__ out)
{
    const int lane = threadIdx.x & 63;
    const int b    = (blockIdx.x << 2) + (threadIdx.x >> 6);

    // wave-uniform target -> SGPR; path-map reads become scalar loads
    const int t     = __builtin_amdgcn_readfirstlane(targets[b]);
    const int start = b & 15;  // per-row level-rotation phase

    int nodes[DEPTH];  // in rotated (pipeline) order j
    int dirs[DEPTH];
#pragma unroll
    for (int j = 0; j < DEPTH; ++j) {
        const int k = (start + j) & 15;
        nodes[j] = path_nodes[t * DEPTH + k];
        dirs[j]  = path_dirs [t * DEPTH + k];
    }

    // features: 4x float2 per lane; lane L owns dims {128q+2L, 128q+2L+1}
    const float2* fb = (const float2*)(features + (size_t)b * FDIM);
    const float2 f0 = fb[lane];
    const float2 f1 = fb[lane + 64];
    const float2 f2 = fb[lane + 128];
    const float2 f3 = fb[lane + 192];

    // weight base for pipeline step j; padding (-1) -> node 0 (hot, masked)
    auto wptr = [&](int j) -> const float4* {
        const int n = nodes[j] < 0 ? 0 : nodes[j];
        return (const float4*)(node_weights + (size_t)n * (FDIM * 2));
    };

    // 4-deep register pipeline: 16 outstanding contiguous 16B loads/wave.
    // w4[lane + 64q] = (w[128q+2L][0], w[128q+2L][1], w[128q+2L+1][0], [1])
    float4 buf[4][4];
#pragma unroll
    for (int j = 0; j < 4; ++j) {
        const float4* p = wptr(j);
        buf[j][0] = p[lane];
        buf[j][1] = p[lane + 64];
        buf[j][2] = p[lane + 128];
        buf[j][3] = p[lane + 192];
    }

    float zp[DEPTH];  // per-lane partial of z = logit0 - logit1, order j
#pragma unroll
    for (int j = 0; j < DEPTH; ++j) {
        const float4 a0 = buf[j & 3][0], a1 = buf[j & 3][1];
        const float4 a2 = buf[j & 3][2], a3 = buf[j & 3][3];
        if (j + 4 < DEPTH) {  // refill the slot just consumed
            const float4* p = wptr(j + 4);
            buf[j & 3][0] = p[lane];
            buf[j & 3][1] = p[lane + 64];
            buf[j & 3][2] = p[lane + 128];
            buf[j & 3][3] = p[lane + 192];
        }
        zp[j] = f0.x * (a0.x - a0.y) + f0.y * (a0.z - a0.w)
              + f1.x * (a1.x - a1.y) + f1.y * (a1.z - a1.w)
              + f2.x * (a2.x - a2.y) + f2.y * (a2.z - a2.w)
              + f3.x * (a3.x - a3.y) + f3.y * (a3.z - a3.w);
    }

    // 16 independent 6-level butterflies (throughput-pipelined)
#pragma unroll
    for (int j = 0; j < DEPTH; ++j) {
#pragma unroll
        for (int off = 32; off; off >>= 1)
            zp[j] += __shfl_xor(zp[j], off, 64);
    }

    // loss = sum_j softplus(-s), s = dir ? -z : z  (order differs from ref
    // by rotation; fp reassociation is well inside the 0.685 threshold)
    float loss = 0.0f;
#pragma unroll
    for (int j = 0; j < DEPTH; ++j) {
        if (nodes[j] >= 0) {
            const float s = (dirs[j] == 0) ? zp[j] : -zp[j];
            loss += fmaxf(-s, 0.0f) + __logf(1.0f + __expf(-fabsf(s)));
        }
    }

    if (lane == 0) out[b] = loss;
}

extern "C" void kernel_launch(void* const* d_in, const int* in_sizes, int n_in,
                              void* d_out, int out_size, void* d_ws, size_t ws_size,
                              hipStream_t stream) {
    const float* features     = (const float*)d_in[0];
    const int*   targets      = (const int*)  d_in[1];
    const float* node_weights = (const float*)d_in[2];
    const int*   path_nodes   = (const int*)  d_in[3];
    const int*   path_dirs    = (const int*)  d_in[4];
    float*       out          = (float*)d_out;

    hstree_loss<<<BATCH / 4, 256, 0, stream>>>(
        features, targets, node_weights, path_nodes, path_dirs, out);
}